// Round 12
// baseline (42.831 us; speedup 1.0000x reference)
//
#include <hip/hip_runtime.h>
#include <hip/hip_fp16.h>
#include <math.h>

typedef unsigned int u32;
typedef __attribute__((ext_vector_type(4))) _Float16 f16x4;  // 4 fp16 in 2 VGPRs
typedef __attribute__((ext_vector_type(4))) float f32x4;     // 16x16 MFMA acc

#define HW 16384
#define NK 100
#define NPAIR 50   // instance-pairs per batch

#define MFMA16(a, b, c) __builtin_amdgcn_mfma_f32_16x16x16f16((a), (b), (c), 0, 0, 0)

// ---------------- helpers ----------------
__device__ __forceinline__ u32 pk2h(float lo, float hi) {    // fp32x2 -> packed fp16 RNE
    return (u32)__half_as_ushort(__float2half_rn(lo))
         | ((u32)__half_as_ushort(__float2half_rn(hi)) << 16);
}
__device__ __forceinline__ float rcpf(float x) {
    float r; asm("v_rcp_f32 %0, %1" : "=v"(r) : "v"(x)); return r;
}

// ---------------- fragment layouts (16x16x16 f16 family mapping) ----------------
// A(16x16): lane = m + 16*(k>>2), elem = k&3   (m = row, k = reduction idx)
// B(16x16): lane = n + 16*(k>>2), elem = k&3   (n = col = pixel)
// D(16x16): lane = n + 16*(m>>2), reg  = m&3   (guide-verified m89)
// => relu(D0) -> B1 for layer1 requires NO cross-lane movement.
//
// Per instance-PAIR (2 instances), rows m = inst_local*8 + ch:
// A0(m,k): k=0:-wx/128, k=1:-wy/128, k=2..9: w0[ch][k], k=10: b0+(wx*sx+wy*sy)/128, k>=11: 0
// A1(m,k): block-diag W1: (m>>3)==(k>>3) ? w1[ch][k&7] : 0
// TAB per pair (40 f32, 160B): [0:16) b1-seed by row m; [16:32) w2 by row m;
//                              [32:34) 0.5*b2[inst0], 0.5*b2[inst1]; [34:40) pad
__global__ __launch_bounds__(256) void pack_kernel(
    const float* __restrict__ cw, const int* __restrict__ ind,
    uint2* __restrict__ A0, uint2* __restrict__ A1, float* __restrict__ TAB)
{
    int id = blockIdx.x * 256 + threadIdx.x;
    if (id < 12800) {                       // ---- A0 ----
        int bp = id >> 6, lane = id & 63;
        int b = bp / NPAIR, p = bp % NPAIR;
        int m = lane & 15, q = lane >> 4;
        int ch = m & 7;
        int inst = 2 * p + (m >> 3);
        int hw = ind[b * NK + inst];
        const float* base = cw + (size_t)b * 169 * HW + hw;
        float sx = (float)(hw & 127), sy = (float)(hw >> 7);
        float vv[4];
        #pragma unroll
        for (int e = 0; e < 4; ++e) {
            int k = 4 * q + e;
            float val = 0.f;
            if (k < 2)
                val = -base[(size_t)(ch * 10 + k) * HW] * 0.0078125f;
            else if (k < 10)
                val = base[(size_t)(ch * 10 + k) * HW];
            else if (k == 10)
                val = base[(size_t)(152 + ch) * HW]
                    + (base[(size_t)(ch * 10) * HW] * sx
                     + base[(size_t)(ch * 10 + 1) * HW] * sy) * 0.0078125f;
            vv[e] = val;
        }
        A0[id] = make_uint2(pk2h(vv[0], vv[1]), pk2h(vv[2], vv[3]));
    } else if (id < 25600) {                // ---- A1 (block-diagonal W1) ----
        int id2 = id - 12800;
        int bp = id2 >> 6, lane = id2 & 63;
        int b = bp / NPAIR, p = bp % NPAIR;
        int m = lane & 15, q = lane >> 4;
        int ch = m & 7;
        int inst = 2 * p + (m >> 3);
        int hw = ind[b * NK + inst];
        const float* base = cw + (size_t)b * 169 * HW + hw;
        float vv[4];
        #pragma unroll
        for (int e = 0; e < 4; ++e) {
            int k = 4 * q + e;
            bool valid = (m >> 3) == (k >> 3);
            vv[e] = valid ? base[(size_t)(80 + ch * 8 + (k & 7)) * HW] : 0.f;
        }
        A1[id2] = make_uint2(pk2h(vv[0], vv[1]), pk2h(vv[2], vv[3]));
    } else if (id < 33600) {                // ---- TAB ----
        int id3 = id - 25600;
        int bp = id3 / 40, t = id3 - bp * 40;
        int b = bp / NPAIR, p = bp % NPAIR;
        float val = 0.f;
        if (t < 16) {                       // b1-seed by row m
            int m = t;
            int hw = ind[b * NK + 2 * p + (m >> 3)];
            val = cw[((size_t)b * 169 + 160 + (m & 7)) * HW + hw];
        } else if (t < 32) {                // w2 by row m
            int m = t - 16;
            int hw = ind[b * NK + 2 * p + (m >> 3)];
            val = cw[((size_t)b * 169 + 144 + (m & 7)) * HW + hw];
        } else if (t < 34) {                // 0.5*b2 per instance
            int hw = ind[b * NK + 2 * p + (t - 32)];
            val = 0.5f * cw[((size_t)b * 169 + 168) * HW + hw];
        }
        TAB[id3] = val;
    }
}

// ---------------- compute: 3-layer MLP via 16x16x16 fp16 MFMA ----------------
// per iter: 16 px x 2 instances; 2 MFMAs; zero cross-lane until final xor-16 fold
__global__ __launch_bounds__(64, 8) void mfma_kernel(
    const float* __restrict__ seg_feat,
    const uint2* __restrict__ A0, const uint2* __restrict__ A1,
    const float* __restrict__ TAB, float* __restrict__ out)
{
    const int lane = threadIdx.x;           // 0..63
    const int q = lane >> 4;                // k-quarter
    const int n = lane & 15;                // pixel column
    const int tile = blockIdx.x;            // 0..1023 (16 px per tile)
    const int b = blockIdx.y;               // 0..3
    const int p0 = blockIdx.z * 25;         // pair chunk

    const int px = tile * 16 + n;

    // B0 fragment: k = 4*q + e over [xp, yp, f0..f7, 1, 0...]
    float f0 = seg_feat[(size_t)(b * 8 + 0) * HW + px];
    float f1 = seg_feat[(size_t)(b * 8 + 1) * HW + px];
    float f2 = seg_feat[(size_t)(b * 8 + 2) * HW + px];
    float f3 = seg_feat[(size_t)(b * 8 + 3) * HW + px];
    float f4 = seg_feat[(size_t)(b * 8 + 4) * HW + px];
    float f5 = seg_feat[(size_t)(b * 8 + 5) * HW + px];
    float f6 = seg_feat[(size_t)(b * 8 + 6) * HW + px];
    float f7 = seg_feat[(size_t)(b * 8 + 7) * HW + px];
    const float xp = (float)(px & 127), yp = (float)(px >> 7);

    float e0, e1, e2, e3;
    if (q == 0)      { e0 = xp; e1 = yp; e2 = f0; e3 = f1; }
    else if (q == 1) { e0 = f2; e1 = f3; e2 = f4; e3 = f5; }
    else if (q == 2) { e0 = f6; e1 = f7; e2 = 1.0f; e3 = 0.f; }
    else             { e0 = 0.f; e1 = 0.f; e2 = 0.f; e3 = 0.f; }
    uint2 b0u = make_uint2(pk2h(e0, e1), pk2h(e2, e3));
    f16x4 B0 = __builtin_bit_cast(f16x4, b0u);

    f32x4 zero = {0.f, 0.f, 0.f, 0.f};

    for (int p = p0; p < p0 + 25; ++p) {
        const int bp = b * NPAIR + p;
        uint2 a0 = A0[bp * 64 + lane];
        uint2 a1 = A1[bp * 64 + lane];
        const float* tb = TAB + bp * 40;
        float4 seed = *(const float4*)(tb + 4 * q);        // b1 for rows 4q+0..3
        float4 w2v  = *(const float4*)(tb + 16 + 4 * q);   // w2 for rows 4q+0..3
        float  b2h  = tb[32 + (lane >> 5)];                // 0.5*b2[inst]

        // layer 0: D0 rows = h0 channels (2 inst x 8 ch), cols = px
        f32x4 d0 = MFMA16(__builtin_bit_cast(f16x4, a0), B0, zero);

        // relu + fp16 pack; D layout == B layout -> direct feed to layer 1
        uint2 b1u = make_uint2(pk2h(fmaxf(d0[0], 0.f), fmaxf(d0[1], 0.f)),
                               pk2h(fmaxf(d0[2], 0.f), fmaxf(d0[3], 0.f)));
        f16x4 B1 = __builtin_bit_cast(f16x4, b1u);

        // layer 1: block-diag W1, acc seeded with b1
        f32x4 d1 = MFMA16(__builtin_bit_cast(f16x4, a1),  B1,
                          __builtin_bit_cast(f32x4, seed));

        // layer 2: per-lane 4-row partial dot (fp32), fold q <-> q^1, sigmoid
        float pz = b2h;
        pz = fmaf(w2v.x, fmaxf(d1[0], 0.f), pz);
        pz = fmaf(w2v.y, fmaxf(d1[1], 0.f), pz);
        pz = fmaf(w2v.z, fmaxf(d1[2], 0.f), pz);
        pz = fmaf(w2v.w, fmaxf(d1[3], 0.f), pz);

        int tz = __builtin_amdgcn_ds_swizzle(__builtin_bit_cast(int, pz), 0x401F); // lane ^ 16
        float z = pz + __builtin_bit_cast(float, tz);
        float o = rcpf(1.f + __expf(-z));

        if ((q & 1) == 0) {   // q0 -> inst0, q2 -> inst1
            out[(size_t)(b * NK + 2 * p + (q >> 1)) * HW + px] = o;
        }
    }
}

extern "C" void kernel_launch(void* const* d_in, const int* in_sizes, int n_in,
                              void* d_out, int out_size, void* d_ws, size_t ws_size,
                              hipStream_t stream) {
    const float* seg_feat    = (const float*)d_in[0];
    const float* conv_weight = (const float*)d_in[1];
    const int*   ind         = (const int*)d_in[2];
    float*       out         = (float*)d_out;

    uint2* A0 = (uint2*)d_ws;                               // 200*64*8   = 102400 B
    uint2* A1 = (uint2*)((char*)d_ws + 102400);             // 102400 B
    float* TAB = (float*)((char*)d_ws + 204800);            // 200*40*4   = 32000 B

    {
        dim3 grid((33600 + 255) / 256), block(256);
        pack_kernel<<<grid, block, 0, stream>>>(conv_weight, ind, A0, A1, TAB);
    }
    {
        dim3 grid(1024, 4, 2), block(64);   // 8192 single-wave blocks = 32 waves/CU
        mfma_kernel<<<grid, block, 0, stream>>>(seg_feat, A0, A1, TAB, out);
    }
}

// Round 14
// 28.525 us; speedup vs baseline: 1.5015x; 1.5015x over previous
//
#include <hip/hip_runtime.h>
#include <hip/hip_fp16.h>
#include <math.h>

typedef unsigned int u32;
typedef __attribute__((ext_vector_type(8))) _Float16 f16x8;  // 8 fp16 in 4 VGPRs
typedef __attribute__((ext_vector_type(16))) float f32x16;   // 32x32 MFMA acc

#define HW 16384
#define NB 4
#define NK 100
#define NGRP 25   // instance-groups of 4 per batch

// ---------------- helpers ----------------
__device__ __forceinline__ u32 pk2h(float lo, float hi) {    // fp32x2 -> packed fp16 RNE
    return (u32)__half_as_ushort(__float2half_rn(lo))
         | ((u32)__half_as_ushort(__float2half_rn(hi)) << 16);
}
__device__ __forceinline__ u32 sx32(u32 v) {                 // opposite 32-lane half's value
    return (u32)__shfl_xor((int)v, 32, 64);
}
__device__ __forceinline__ float sx32f(float v) {
    return __shfl_xor(v, 32, 64);
}
__device__ __forceinline__ float rcpf(float x) {
    float r; asm("v_rcp_f32 %0, %1" : "=v"(r) : "v"(x)); return r;
}

// ---------------- pack: gather conv_weight -> MFMA fragment layouts (fp16) ----------------
// (byte-identical to the R8-verified pack kernel)
// A0: 100 groups x 64 lanes x 4 u32; A1: 100 groups x 2 frags x 64 lanes x 4 u32
// WT: 100 groups x 80 f32: [0:16) b1-seed lo; [16:32) b1-seed hi; [32:48) w2 lo;
//     [48:64) w2 hi; [64:68) 0.5*b2; [68:80) pad
__global__ __launch_bounds__(256) void pack_kernel(
    const float* __restrict__ cw, const int* __restrict__ ind,
    u32* __restrict__ A0, u32* __restrict__ A1, float* __restrict__ WT)
{
    int id = blockIdx.x * 256 + threadIdx.x;
    if (id < 25600) {                       // ---- A0 ----
        int bg = id >> 8, rem = id & 255;
        int lane = rem >> 2, reg = rem & 3;
        int b = bg / NGRP, g = bg % NGRP;
        int row = lane & 31;
        int inst = g * 4 + (row >> 3);
        int ch = row & 7;
        int hw = ind[b * NK + inst];
        const float* base = cw + (size_t)b * 169 * HW + hw;
        float sx = (float)(hw & 127), sy = (float)(hw >> 7);
        float v[2];
        #pragma unroll
        for (int j = 0; j < 2; ++j) {
            int k = ((lane >> 5) << 3) + reg * 2 + j;
            float val = 0.f;
            if (k < 2)
                val = -base[(size_t)(ch * 10 + k) * HW] * 0.0078125f;
            else if (k < 10)
                val = base[(size_t)(ch * 10 + k) * HW];
            else if (k == 10)
                val = base[(size_t)(152 + ch) * HW]
                    + (base[(size_t)(ch * 10) * HW] * sx
                     + base[(size_t)(ch * 10 + 1) * HW] * sy) * 0.0078125f;
            v[j] = val;
        }
        A0[id] = pk2h(v[0], v[1]);
    } else if (id < 76800) {                // ---- A1 (block-diagonal W1) ----
        int id2 = id - 25600;
        int bg = id2 >> 9, r2 = id2 & 511;
        int frag = r2 >> 8;
        int lane = (r2 >> 2) & 63, reg = r2 & 3;
        int b = bg / NGRP, g = bg % NGRP;
        int row = lane & 31;
        int inst = g * 4 + (row >> 3);
        int hw = ind[b * NK + inst];
        const float* base = cw + (size_t)b * 169 * HW + hw;
        float v[2];
        #pragma unroll
        for (int j = 0; j < 2; ++j) {
            int k = ((lane >> 5) << 3) + reg * 2 + j;
            bool valid = ((row >> 4) == frag) && (((row >> 3) & 1) == (k >> 3));
            v[j] = valid ? base[(size_t)(80 + (row & 7) * 8 + (k & 7)) * HW] : 0.f;
        }
        A1[id2] = pk2h(v[0], v[1]);
    } else if (id < 84800) {                // ---- WT (fp32 tables) ----
        int id3 = id - 76800;
        int bg = id3 / 80, q = id3 - bg * 80;
        int b = bg / NGRP, g = bg % NGRP;
        float val = 0.f;
        if (q < 32) {                       // d1-init = b1[row]
            int hi = q >> 4, e = q & 15;
            int row = (e & 3) + 8 * (e >> 2) + 4 * hi;
            int inst = g * 4 + (row >> 3);
            int hw = ind[b * NK + inst];
            val = cw[(size_t)b * 169 * HW + (size_t)(160 + (row & 7)) * HW + hw];
        } else if (q < 64) {                // w2 halves
            int half = (q - 32) >> 4, q2 = (q - 32) & 15;
            int n = q2 >> 2, j = q2 & 3;
            int hw = ind[b * NK + g * 4 + n];
            val = cw[(size_t)b * 169 * HW + (size_t)(144 + half * 4 + j) * HW + hw];
        } else if (q < 68) {                // 0.5*b2
            int n = q - 64;
            int hw = ind[b * NK + g * 4 + n];
            val = 0.5f * cw[(size_t)b * 169 * HW + (size_t)168 * HW + hw];
        }
        WT[id3] = val;
    }
}

// ---------------- compute: 3-layer MLP via fp16 MFMA, 2 tiles x 32 px x 4 inst ----------------
__global__ __launch_bounds__(64, 4) void mfma_kernel(
    const float* __restrict__ seg_feat,
    const u32* __restrict__ A0, const u32* __restrict__ A1,
    const float* __restrict__ WT, float* __restrict__ out)
{
    const int lane = threadIdx.x;           // 0..63
    const bool hi = lane >= 32;
    const int col = lane & 31;              // pixel column within tile
    const int tile = blockIdx.x;            // 0..255 (64 px per block)
    const int b = blockIdx.y;               // 0..3
    const int z = blockIdx.z;               // 0..3 -> groups 7/6/6/6
    const int g0 = (z == 0) ? 0 : (6 * z + 1);
    const int g1 = 6 * z + 7;

    const int pxa = tile * 64 + col;
    const int pxb = pxa + 32;

    // B0 fragments (K=16 x N=32 px): k = 8*(lane>=32)+j = [xp,yp,f0..f5 | f6,f7,1,0...]
    float fa[8], fb[8];
    #pragma unroll
    for (int c = 0; c < 8; ++c) {
        fa[c] = seg_feat[(size_t)(b * 8 + c) * HW + pxa];
        fb[c] = seg_feat[(size_t)(b * 8 + c) * HW + pxb];
    }
    const float xpa = (float)(pxa & 127), ypa = (float)(pxa >> 7);
    const float xpb = (float)(pxb & 127), ypb = (float)(pxb >> 7);

    uint4 b0ua = make_uint4(hi ? pk2h(fa[6], fa[7]) : pk2h(xpa, ypa),
                            hi ? 0x00003C00u : pk2h(fa[0], fa[1]),
                            hi ? 0u : pk2h(fa[2], fa[3]),
                            hi ? 0u : pk2h(fa[4], fa[5]));
    uint4 b0ub = make_uint4(hi ? pk2h(fb[6], fb[7]) : pk2h(xpb, ypb),
                            hi ? 0x00003C00u : pk2h(fb[0], fb[1]),
                            hi ? 0u : pk2h(fb[2], fb[3]),
                            hi ? 0u : pk2h(fb[4], fb[5]));
    f16x8 B0a = __builtin_bit_cast(f16x8, b0ua);
    f16x8 B0b = __builtin_bit_cast(f16x8, b0ub);

    f32x16 zero;
    #pragma unroll
    for (int i = 0; i < 16; ++i) zero[i] = 0.f;

    for (int g = g0; g < g1; ++g) {
        const int bg = b * NGRP + g;
        uint4 a0w  = ((const uint4*)A0)[bg * 64 + lane];
        uint4 a1aw = ((const uint4*)A1)[(bg * 2 + 0) * 64 + lane];
        uint4 a1bw = ((const uint4*)A1)[(bg * 2 + 1) * 64 + lane];
        const float* wb = WT + bg * 80;
        const float4* bi = (const float4*)(wb + (hi ? 16 : 0));
        float4 i0 = bi[0], i1 = bi[1], i2 = bi[2], i3 = bi[3];
        const float4* wv = (const float4*)(wb + 32 + (hi ? 16 : 0));
        float4 wn0 = wv[0], wn1 = wv[1], wn2 = wv[2], wn3 = wv[3];
        float4 bw = *(const float4*)(wb + 64);     // 0.5*b2[0..3]

        // ================= tile a =================
        {
            f32x16 d0 = __builtin_amdgcn_mfma_f32_32x32x16_f16(
                __builtin_bit_cast(f16x8, a0w), B0a, zero, 0, 0, 0);

            // relu + fp16-pack; cross-half exchange via shfl_xor (no inline asm)
            u32 u0 = pk2h(fmaxf(d0[0], 0.f),  fmaxf(d0[1], 0.f));   // rows 0,1 / 4,5
            u32 u1 = pk2h(fmaxf(d0[2], 0.f),  fmaxf(d0[3], 0.f));   // rows 2,3 / 6,7
            u32 u2 = pk2h(fmaxf(d0[4], 0.f),  fmaxf(d0[5], 0.f));   // rows 8,9 / 12,13
            u32 u3 = pk2h(fmaxf(d0[6], 0.f),  fmaxf(d0[7], 0.f));   // rows 10,11 / 14,15
            u32 u4 = pk2h(fmaxf(d0[8], 0.f),  fmaxf(d0[9], 0.f));   // rows 16,17 / 20,21
            u32 u5 = pk2h(fmaxf(d0[10], 0.f), fmaxf(d0[11], 0.f));  // rows 18,19 / 22,23
            u32 u6 = pk2h(fmaxf(d0[12], 0.f), fmaxf(d0[13], 0.f));  // rows 24,25 / 28,29
            u32 u7 = pk2h(fmaxf(d0[14], 0.f), fmaxf(d0[15], 0.f));  // rows 26,27 / 30,31
            u32 t0 = sx32(u0), t1 = sx32(u1), t2 = sx32(u2), t3 = sx32(u3);
            u32 t4 = sx32(u4), t5 = sx32(u5), t6 = sx32(u6), t7 = sx32(u7);
            // B1a word_j: lo lanes k=(2j,2j+1) ; hi lanes k=(2j+8,2j+9)
            uint4 b1au = make_uint4(hi ? t2 : u0, hi ? t3 : u1,
                                    hi ? u2 : t0, hi ? u3 : t1);
            uint4 b1bu = make_uint4(hi ? t6 : u4, hi ? t7 : u5,
                                    hi ? u6 : t4, hi ? u7 : t5);

            f32x16 d1;
            d1[0]  = i0.x; d1[1]  = i0.y; d1[2]  = i0.z; d1[3]  = i0.w;
            d1[4]  = i1.x; d1[5]  = i1.y; d1[6]  = i1.z; d1[7]  = i1.w;
            d1[8]  = i2.x; d1[9]  = i2.y; d1[10] = i2.z; d1[11] = i2.w;
            d1[12] = i3.x; d1[13] = i3.y; d1[14] = i3.z; d1[15] = i3.w;
            d1 = __builtin_amdgcn_mfma_f32_32x32x16_f16(
                __builtin_bit_cast(f16x8, a1aw), __builtin_bit_cast(f16x8, b1au), d1, 0, 0, 0);
            d1 = __builtin_amdgcn_mfma_f32_32x32x16_f16(
                __builtin_bit_cast(f16x8, a1bw), __builtin_bit_cast(f16x8, b1bu), d1, 0, 0, 0);

            float pz0 = bw.x, pz1 = bw.y, pz2 = bw.z, pz3 = bw.w;
            pz0 = fmaf(wn0.x, fmaxf(d1[0], 0.f), pz0);
            pz0 = fmaf(wn0.y, fmaxf(d1[1], 0.f), pz0);
            pz0 = fmaf(wn0.z, fmaxf(d1[2], 0.f), pz0);
            pz0 = fmaf(wn0.w, fmaxf(d1[3], 0.f), pz0);
            pz1 = fmaf(wn1.x, fmaxf(d1[4], 0.f), pz1);
            pz1 = fmaf(wn1.y, fmaxf(d1[5], 0.f), pz1);
            pz1 = fmaf(wn1.z, fmaxf(d1[6], 0.f), pz1);
            pz1 = fmaf(wn1.w, fmaxf(d1[7], 0.f), pz1);
            pz2 = fmaf(wn2.x, fmaxf(d1[8], 0.f), pz2);
            pz2 = fmaf(wn2.y, fmaxf(d1[9], 0.f), pz2);
            pz2 = fmaf(wn2.z, fmaxf(d1[10], 0.f), pz2);
            pz2 = fmaf(wn2.w, fmaxf(d1[11], 0.f), pz2);
            pz3 = fmaf(wn3.x, fmaxf(d1[12], 0.f), pz3);
            pz3 = fmaf(wn3.y, fmaxf(d1[13], 0.f), pz3);
            pz3 = fmaf(wn3.z, fmaxf(d1[14], 0.f), pz3);
            pz3 = fmaf(wn3.w, fmaxf(d1[15], 0.f), pz3);

            // z for inst n = pz_n + opposite-half pz_n; pick inst by half
            float zi0 = pz0 + sx32f(pz0);
            float zi1 = pz1 + sx32f(pz1);
            float zi2 = pz2 + sx32f(pz2);
            float zi3 = pz3 + sx32f(pz3);
            float z01 = hi ? zi1 : zi0;
            float z23 = hi ? zi3 : zi2;

            float o01 = rcpf(1.f + __expf(-z01));
            float o23 = rcpf(1.f + __expf(-z23));

            size_t obase = (size_t)(b * NK + g * 4) * HW + pxa;
            out[obase + (size_t)(hi ? 1 : 0) * HW] = o01;
            out[obase + (size_t)(hi ? 3 : 2) * HW] = o23;
        }
        // ================= tile b =================
        {
            f32x16 d0 = __builtin_amdgcn_mfma_f32_32x32x16_f16(
                __builtin_bit_cast(f16x8, a0w), B0b, zero, 0, 0, 0);

            u32 u0 = pk2h(fmaxf(d0[0], 0.f),  fmaxf(d0[1], 0.f));
            u32 u1 = pk2h(fmaxf(d0[2], 0.f),  fmaxf(d0[3], 0.f));
            u32 u2 = pk2h(fmaxf(d0[4], 0.f),  fmaxf(d0[5], 0.f));
            u32 u3 = pk2h(fmaxf(d0[6], 0.f),  fmaxf(d0[7], 0.f));
            u32 u4 = pk2h(fmaxf(d0[8], 0.f),  fmaxf(d0[9], 0.f));
            u32 u5 = pk2h(fmaxf(d0[10], 0.f), fmaxf(d0[11], 0.f));
            u32 u6 = pk2h(fmaxf(d0[12], 0.f), fmaxf(d0[13], 0.f));
            u32 u7 = pk2h(fmaxf(d0[14], 0.f), fmaxf(d0[15], 0.f));
            u32 t0 = sx32(u0), t1 = sx32(u1), t2 = sx32(u2), t3 = sx32(u3);
            u32 t4 = sx32(u4), t5 = sx32(u5), t6 = sx32(u6), t7 = sx32(u7);
            uint4 b1au = make_uint4(hi ? t2 : u0, hi ? t3 : u1,
                                    hi ? u2 : t0, hi ? u3 : t1);
            uint4 b1bu = make_uint4(hi ? t6 : u4, hi ? t7 : u5,
                                    hi ? u6 : t4, hi ? u7 : t5);

            f32x16 d1;
            d1[0]  = i0.x; d1[1]  = i0.y; d1[2]  = i0.z; d1[3]  = i0.w;
            d1[4]  = i1.x; d1[5]  = i1.y; d1[6]  = i1.z; d1[7]  = i1.w;
            d1[8]  = i2.x; d1[9]  = i2.y; d1[10] = i2.z; d1[11] = i2.w;
            d1[12] = i3.x; d1[13] = i3.y; d1[14] = i3.z; d1[15] = i3.w;
            d1 = __builtin_amdgcn_mfma_f32_32x32x16_f16(
                __builtin_bit_cast(f16x8, a1aw), __builtin_bit_cast(f16x8, b1au), d1, 0, 0, 0);
            d1 = __builtin_amdgcn_mfma_f32_32x32x16_f16(
                __builtin_bit_cast(f16x8, a1bw), __builtin_bit_cast(f16x8, b1bu), d1, 0, 0, 0);

            float pz0 = bw.x, pz1 = bw.y, pz2 = bw.z, pz3 = bw.w;
            pz0 = fmaf(wn0.x, fmaxf(d1[0], 0.f), pz0);
            pz0 = fmaf(wn0.y, fmaxf(d1[1], 0.f), pz0);
            pz0 = fmaf(wn0.z, fmaxf(d1[2], 0.f), pz0);
            pz0 = fmaf(wn0.w, fmaxf(d1[3], 0.f), pz0);
            pz1 = fmaf(wn1.x, fmaxf(d1[4], 0.f), pz1);
            pz1 = fmaf(wn1.y, fmaxf(d1[5], 0.f), pz1);
            pz1 = fmaf(wn1.z, fmaxf(d1[6], 0.f), pz1);
            pz1 = fmaf(wn1.w, fmaxf(d1[7], 0.f), pz1);
            pz2 = fmaf(wn2.x, fmaxf(d1[8], 0.f), pz2);
            pz2 = fmaf(wn2.y, fmaxf(d1[9], 0.f), pz2);
            pz2 = fmaf(wn2.z, fmaxf(d1[10], 0.f), pz2);
            pz2 = fmaf(wn2.w, fmaxf(d1[11], 0.f), pz2);
            pz3 = fmaf(wn3.x, fmaxf(d1[12], 0.f), pz3);
            pz3 = fmaf(wn3.y, fmaxf(d1[13], 0.f), pz3);
            pz3 = fmaf(wn3.z, fmaxf(d1[14], 0.f), pz3);
            pz3 = fmaf(wn3.w, fmaxf(d1[15], 0.f), pz3);

            float zi0 = pz0 + sx32f(pz0);
            float zi1 = pz1 + sx32f(pz1);
            float zi2 = pz2 + sx32f(pz2);
            float zi3 = pz3 + sx32f(pz3);
            float z01 = hi ? zi1 : zi0;
            float z23 = hi ? zi3 : zi2;

            float o01 = rcpf(1.f + __expf(-z01));
            float o23 = rcpf(1.f + __expf(-z23));

            size_t obase = (size_t)(b * NK + g * 4) * HW + pxb;
            out[obase + (size_t)(hi ? 1 : 0) * HW] = o01;
            out[obase + (size_t)(hi ? 3 : 2) * HW] = o23;
        }
    }
}

extern "C" void kernel_launch(void* const* d_in, const int* in_sizes, int n_in,
                              void* d_out, int out_size, void* d_ws, size_t ws_size,
                              hipStream_t stream) {
    const float* seg_feat    = (const float*)d_in[0];
    const float* conv_weight = (const float*)d_in[1];
    const int*   ind         = (const int*)d_in[2];
    float*       out         = (float*)d_out;

    u32*   A0 = (u32*)d_ws;                                 // 102400 B
    u32*   A1 = (u32*)((char*)d_ws + 102400);               // 204800 B
    float* WT = (float*)((char*)d_ws + 307200);             // 32000 B

    {
        dim3 grid((84800 + 255) / 256), block(256);
        pack_kernel<<<grid, block, 0, stream>>>(conv_weight, ind, A0, A1, WT);
    }
    {
        dim3 grid(256, 4, 4), block(64);    // 4096 single-wave blocks
        mfma_kernel<<<grid, block, 0, stream>>>(seg_feat, A0, A1, WT, out);
    }
}

// Round 15
// 27.478 us; speedup vs baseline: 1.5587x; 1.0381x over previous
//
#include <hip/hip_runtime.h>
#include <hip/hip_fp16.h>
#include <math.h>

typedef unsigned int u32;
typedef __attribute__((ext_vector_type(8))) _Float16 f16x8;  // 8 fp16 in 4 VGPRs
typedef __attribute__((ext_vector_type(16))) float f32x16;   // 32x32 MFMA acc

#define HW 16384
#define NB 4
#define NK 100
#define NGRP 25   // instance-groups of 4 per batch

// ---------------- helpers ----------------
__device__ __forceinline__ u32 pk2h(float lo, float hi) {    // fp32x2 -> packed fp16 RNE
    return (u32)__half_as_ushort(__float2half_rn(lo))
         | ((u32)__half_as_ushort(__float2half_rn(hi)) << 16);
}
__device__ __forceinline__ u32 sx32(u32 v) {                 // opposite 32-lane half's value
    return (u32)__shfl_xor((int)v, 32, 64);
}
__device__ __forceinline__ float sx32f(float v) {
    return __shfl_xor(v, 32, 64);
}
__device__ __forceinline__ float rcpf(float x) {
    float r; asm("v_rcp_f32 %0, %1" : "=v"(r) : "v"(x)); return r;
}

// ---------------- pack: gather conv_weight -> MFMA fragment layouts (fp16) ----------------
// (byte-identical to the R8/R14-verified pack kernel)
__global__ __launch_bounds__(256) void pack_kernel(
    const float* __restrict__ cw, const int* __restrict__ ind,
    u32* __restrict__ A0, u32* __restrict__ A1, float* __restrict__ WT)
{
    int id = blockIdx.x * 256 + threadIdx.x;
    if (id < 25600) {                       // ---- A0 ----
        int bg = id >> 8, rem = id & 255;
        int lane = rem >> 2, reg = rem & 3;
        int b = bg / NGRP, g = bg % NGRP;
        int row = lane & 31;
        int inst = g * 4 + (row >> 3);
        int ch = row & 7;
        int hw = ind[b * NK + inst];
        const float* base = cw + (size_t)b * 169 * HW + hw;
        float sx = (float)(hw & 127), sy = (float)(hw >> 7);
        float v[2];
        #pragma unroll
        for (int j = 0; j < 2; ++j) {
            int k = ((lane >> 5) << 3) + reg * 2 + j;
            float val = 0.f;
            if (k < 2)
                val = -base[(size_t)(ch * 10 + k) * HW] * 0.0078125f;
            else if (k < 10)
                val = base[(size_t)(ch * 10 + k) * HW];
            else if (k == 10)
                val = base[(size_t)(152 + ch) * HW]
                    + (base[(size_t)(ch * 10) * HW] * sx
                     + base[(size_t)(ch * 10 + 1) * HW] * sy) * 0.0078125f;
            v[j] = val;
        }
        A0[id] = pk2h(v[0], v[1]);
    } else if (id < 76800) {                // ---- A1 (block-diagonal W1) ----
        int id2 = id - 25600;
        int bg = id2 >> 9, r2 = id2 & 511;
        int frag = r2 >> 8;
        int lane = (r2 >> 2) & 63, reg = r2 & 3;
        int b = bg / NGRP, g = bg % NGRP;
        int row = lane & 31;
        int inst = g * 4 + (row >> 3);
        int hw = ind[b * NK + inst];
        const float* base = cw + (size_t)b * 169 * HW + hw;
        float v[2];
        #pragma unroll
        for (int j = 0; j < 2; ++j) {
            int k = ((lane >> 5) << 3) + reg * 2 + j;
            bool valid = ((row >> 4) == frag) && (((row >> 3) & 1) == (k >> 3));
            v[j] = valid ? base[(size_t)(80 + (row & 7) * 8 + (k & 7)) * HW] : 0.f;
        }
        A1[id2] = pk2h(v[0], v[1]);
    } else if (id < 84800) {                // ---- WT (fp32 tables) ----
        int id3 = id - 76800;
        int bg = id3 / 80, q = id3 - bg * 80;
        int b = bg / NGRP, g = bg % NGRP;
        float val = 0.f;
        if (q < 32) {                       // d1-init = b1[row]
            int hi = q >> 4, e = q & 15;
            int row = (e & 3) + 8 * (e >> 2) + 4 * hi;
            int inst = g * 4 + (row >> 3);
            int hw = ind[b * NK + inst];
            val = cw[(size_t)b * 169 * HW + (size_t)(160 + (row & 7)) * HW + hw];
        } else if (q < 64) {                // w2 halves
            int half = (q - 32) >> 4, q2 = (q - 32) & 15;
            int n = q2 >> 2, j = q2 & 3;
            int hw = ind[b * NK + g * 4 + n];
            val = cw[(size_t)b * 169 * HW + (size_t)(144 + half * 4 + j) * HW + hw];
        } else if (q < 68) {                // 0.5*b2
            int n = q - 64;
            int hw = ind[b * NK + g * 4 + n];
            val = 0.5f * cw[(size_t)b * 169 * HW + (size_t)168 * HW + hw];
        }
        WT[id3] = val;
    }
}

// ---------------- compute: 3-layer MLP via fp16 MFMA, 2 tiles x 32 px x 4 inst ----------------
// Body byte-identical to R14 (passed, 28.5us); adds clean loop-peel prefetch of
// next group's A-fragments (no undef values, no tied-operand asm anywhere).
__global__ __launch_bounds__(64, 4) void mfma_kernel(
    const float* __restrict__ seg_feat,
    const u32* __restrict__ A0, const u32* __restrict__ A1,
    const float* __restrict__ WT, float* __restrict__ out)
{
    const int lane = threadIdx.x;           // 0..63
    const bool hi = lane >= 32;
    const int col = lane & 31;              // pixel column within tile
    const int tile = blockIdx.x;            // 0..255 (64 px per block)
    const int b = blockIdx.y;               // 0..3
    const int z = blockIdx.z;               // 0..3 -> groups 7/6/6/6
    const int g0 = (z == 0) ? 0 : (6 * z + 1);
    const int g1 = 6 * z + 7;

    const int pxa = tile * 64 + col;
    const int pxb = pxa + 32;

    // B0 fragments (K=16 x N=32 px): k = 8*(lane>=32)+j = [xp,yp,f0..f5 | f6,f7,1,0...]
    float fa[8], fb[8];
    #pragma unroll
    for (int c = 0; c < 8; ++c) {
        fa[c] = seg_feat[(size_t)(b * 8 + c) * HW + pxa];
        fb[c] = seg_feat[(size_t)(b * 8 + c) * HW + pxb];
    }
    const float xpa = (float)(pxa & 127), ypa = (float)(pxa >> 7);
    const float xpb = (float)(pxb & 127), ypb = (float)(pxb >> 7);

    uint4 b0ua = make_uint4(hi ? pk2h(fa[6], fa[7]) : pk2h(xpa, ypa),
                            hi ? 0x00003C00u : pk2h(fa[0], fa[1]),
                            hi ? 0u : pk2h(fa[2], fa[3]),
                            hi ? 0u : pk2h(fa[4], fa[5]));
    uint4 b0ub = make_uint4(hi ? pk2h(fb[6], fb[7]) : pk2h(xpb, ypb),
                            hi ? 0x00003C00u : pk2h(fb[0], fb[1]),
                            hi ? 0u : pk2h(fb[2], fb[3]),
                            hi ? 0u : pk2h(fb[4], fb[5]));
    f16x8 B0a = __builtin_bit_cast(f16x8, b0ua);
    f16x8 B0b = __builtin_bit_cast(f16x8, b0ub);

    f32x16 zero;
    #pragma unroll
    for (int i = 0; i < 16; ++i) zero[i] = 0.f;

    // one-group body (R14-verified math), inlined lambda
    auto group_body = [&](int g, int bg, uint4 a0w, uint4 a1aw, uint4 a1bw) {
        const float* wb = WT + bg * 80;
        const float4* bi = (const float4*)(wb + (hi ? 16 : 0));
        float4 i0 = bi[0], i1 = bi[1], i2 = bi[2], i3 = bi[3];
        const float4* wv = (const float4*)(wb + 32 + (hi ? 16 : 0));
        float4 wn0 = wv[0], wn1 = wv[1], wn2 = wv[2], wn3 = wv[3];
        float4 bw = *(const float4*)(wb + 64);     // 0.5*b2[0..3]

        // ================= tile a =================
        {
            f32x16 d0 = __builtin_amdgcn_mfma_f32_32x32x16_f16(
                __builtin_bit_cast(f16x8, a0w), B0a, zero, 0, 0, 0);

            u32 u0 = pk2h(fmaxf(d0[0], 0.f),  fmaxf(d0[1], 0.f));
            u32 u1 = pk2h(fmaxf(d0[2], 0.f),  fmaxf(d0[3], 0.f));
            u32 u2 = pk2h(fmaxf(d0[4], 0.f),  fmaxf(d0[5], 0.f));
            u32 u3 = pk2h(fmaxf(d0[6], 0.f),  fmaxf(d0[7], 0.f));
            u32 u4 = pk2h(fmaxf(d0[8], 0.f),  fmaxf(d0[9], 0.f));
            u32 u5 = pk2h(fmaxf(d0[10], 0.f), fmaxf(d0[11], 0.f));
            u32 u6 = pk2h(fmaxf(d0[12], 0.f), fmaxf(d0[13], 0.f));
            u32 u7 = pk2h(fmaxf(d0[14], 0.f), fmaxf(d0[15], 0.f));
            u32 t0 = sx32(u0), t1 = sx32(u1), t2 = sx32(u2), t3 = sx32(u3);
            u32 t4 = sx32(u4), t5 = sx32(u5), t6 = sx32(u6), t7 = sx32(u7);
            uint4 b1au = make_uint4(hi ? t2 : u0, hi ? t3 : u1,
                                    hi ? u2 : t0, hi ? u3 : t1);
            uint4 b1bu = make_uint4(hi ? t6 : u4, hi ? t7 : u5,
                                    hi ? u6 : t4, hi ? u7 : t5);

            f32x16 d1;
            d1[0]  = i0.x; d1[1]  = i0.y; d1[2]  = i0.z; d1[3]  = i0.w;
            d1[4]  = i1.x; d1[5]  = i1.y; d1[6]  = i1.z; d1[7]  = i1.w;
            d1[8]  = i2.x; d1[9]  = i2.y; d1[10] = i2.z; d1[11] = i2.w;
            d1[12] = i3.x; d1[13] = i3.y; d1[14] = i3.z; d1[15] = i3.w;
            d1 = __builtin_amdgcn_mfma_f32_32x32x16_f16(
                __builtin_bit_cast(f16x8, a1aw), __builtin_bit_cast(f16x8, b1au), d1, 0, 0, 0);
            d1 = __builtin_amdgcn_mfma_f32_32x32x16_f16(
                __builtin_bit_cast(f16x8, a1bw), __builtin_bit_cast(f16x8, b1bu), d1, 0, 0, 0);

            float pz0 = bw.x, pz1 = bw.y, pz2 = bw.z, pz3 = bw.w;
            pz0 = fmaf(wn0.x, fmaxf(d1[0], 0.f), pz0);
            pz0 = fmaf(wn0.y, fmaxf(d1[1], 0.f), pz0);
            pz0 = fmaf(wn0.z, fmaxf(d1[2], 0.f), pz0);
            pz0 = fmaf(wn0.w, fmaxf(d1[3], 0.f), pz0);
            pz1 = fmaf(wn1.x, fmaxf(d1[4], 0.f), pz1);
            pz1 = fmaf(wn1.y, fmaxf(d1[5], 0.f), pz1);
            pz1 = fmaf(wn1.z, fmaxf(d1[6], 0.f), pz1);
            pz1 = fmaf(wn1.w, fmaxf(d1[7], 0.f), pz1);
            pz2 = fmaf(wn2.x, fmaxf(d1[8], 0.f), pz2);
            pz2 = fmaf(wn2.y, fmaxf(d1[9], 0.f), pz2);
            pz2 = fmaf(wn2.z, fmaxf(d1[10], 0.f), pz2);
            pz2 = fmaf(wn2.w, fmaxf(d1[11], 0.f), pz2);
            pz3 = fmaf(wn3.x, fmaxf(d1[12], 0.f), pz3);
            pz3 = fmaf(wn3.y, fmaxf(d1[13], 0.f), pz3);
            pz3 = fmaf(wn3.z, fmaxf(d1[14], 0.f), pz3);
            pz3 = fmaf(wn3.w, fmaxf(d1[15], 0.f), pz3);

            float zi0 = pz0 + sx32f(pz0);
            float zi1 = pz1 + sx32f(pz1);
            float zi2 = pz2 + sx32f(pz2);
            float zi3 = pz3 + sx32f(pz3);
            float z01 = hi ? zi1 : zi0;
            float z23 = hi ? zi3 : zi2;

            float o01 = rcpf(1.f + __expf(-z01));
            float o23 = rcpf(1.f + __expf(-z23));

            size_t obase = (size_t)(b * NK + g * 4) * HW + pxa;
            out[obase + (size_t)(hi ? 1 : 0) * HW] = o01;
            out[obase + (size_t)(hi ? 3 : 2) * HW] = o23;
        }
        // ================= tile b =================
        {
            f32x16 d0 = __builtin_amdgcn_mfma_f32_32x32x16_f16(
                __builtin_bit_cast(f16x8, a0w), B0b, zero, 0, 0, 0);

            u32 u0 = pk2h(fmaxf(d0[0], 0.f),  fmaxf(d0[1], 0.f));
            u32 u1 = pk2h(fmaxf(d0[2], 0.f),  fmaxf(d0[3], 0.f));
            u32 u2 = pk2h(fmaxf(d0[4], 0.f),  fmaxf(d0[5], 0.f));
            u32 u3 = pk2h(fmaxf(d0[6], 0.f),  fmaxf(d0[7], 0.f));
            u32 u4 = pk2h(fmaxf(d0[8], 0.f),  fmaxf(d0[9], 0.f));
            u32 u5 = pk2h(fmaxf(d0[10], 0.f), fmaxf(d0[11], 0.f));
            u32 u6 = pk2h(fmaxf(d0[12], 0.f), fmaxf(d0[13], 0.f));
            u32 u7 = pk2h(fmaxf(d0[14], 0.f), fmaxf(d0[15], 0.f));
            u32 t0 = sx32(u0), t1 = sx32(u1), t2 = sx32(u2), t3 = sx32(u3);
            u32 t4 = sx32(u4), t5 = sx32(u5), t6 = sx32(u6), t7 = sx32(u7);
            uint4 b1au = make_uint4(hi ? t2 : u0, hi ? t3 : u1,
                                    hi ? u2 : t0, hi ? u3 : t1);
            uint4 b1bu = make_uint4(hi ? t6 : u4, hi ? t7 : u5,
                                    hi ? u6 : t4, hi ? u7 : t5);

            f32x16 d1;
            d1[0]  = i0.x; d1[1]  = i0.y; d1[2]  = i0.z; d1[3]  = i0.w;
            d1[4]  = i1.x; d1[5]  = i1.y; d1[6]  = i1.z; d1[7]  = i1.w;
            d1[8]  = i2.x; d1[9]  = i2.y; d1[10] = i2.z; d1[11] = i2.w;
            d1[12] = i3.x; d1[13] = i3.y; d1[14] = i3.z; d1[15] = i3.w;
            d1 = __builtin_amdgcn_mfma_f32_32x32x16_f16(
                __builtin_bit_cast(f16x8, a1aw), __builtin_bit_cast(f16x8, b1au), d1, 0, 0, 0);
            d1 = __builtin_amdgcn_mfma_f32_32x32x16_f16(
                __builtin_bit_cast(f16x8, a1bw), __builtin_bit_cast(f16x8, b1bu), d1, 0, 0, 0);

            float pz0 = bw.x, pz1 = bw.y, pz2 = bw.z, pz3 = bw.w;
            pz0 = fmaf(wn0.x, fmaxf(d1[0], 0.f), pz0);
            pz0 = fmaf(wn0.y, fmaxf(d1[1], 0.f), pz0);
            pz0 = fmaf(wn0.z, fmaxf(d1[2], 0.f), pz0);
            pz0 = fmaf(wn0.w, fmaxf(d1[3], 0.f), pz0);
            pz1 = fmaf(wn1.x, fmaxf(d1[4], 0.f), pz1);
            pz1 = fmaf(wn1.y, fmaxf(d1[5], 0.f), pz1);
            pz1 = fmaf(wn1.z, fmaxf(d1[6], 0.f), pz1);
            pz1 = fmaf(wn1.w, fmaxf(d1[7], 0.f), pz1);
            pz2 = fmaf(wn2.x, fmaxf(d1[8], 0.f), pz2);
            pz2 = fmaf(wn2.y, fmaxf(d1[9], 0.f), pz2);
            pz2 = fmaf(wn2.z, fmaxf(d1[10], 0.f), pz2);
            pz2 = fmaf(wn2.w, fmaxf(d1[11], 0.f), pz2);
            pz3 = fmaf(wn3.x, fmaxf(d1[12], 0.f), pz3);
            pz3 = fmaf(wn3.y, fmaxf(d1[13], 0.f), pz3);
            pz3 = fmaf(wn3.z, fmaxf(d1[14], 0.f), pz3);
            pz3 = fmaf(wn3.w, fmaxf(d1[15], 0.f), pz3);

            float zi0 = pz0 + sx32f(pz0);
            float zi1 = pz1 + sx32f(pz1);
            float zi2 = pz2 + sx32f(pz2);
            float zi3 = pz3 + sx32f(pz3);
            float z01 = hi ? zi1 : zi0;
            float z23 = hi ? zi3 : zi2;

            float o01 = rcpf(1.f + __expf(-z01));
            float o23 = rcpf(1.f + __expf(-z23));

            size_t obase = (size_t)(b * NK + g * 4) * HW + pxb;
            out[obase + (size_t)(hi ? 1 : 0) * HW] = o01;
            out[obase + (size_t)(hi ? 3 : 2) * HW] = o23;
        }
    };

    const uint4* A0p = (const uint4*)A0;
    const uint4* A1p = (const uint4*)A1;

    // prologue: first group's fragments (always valid: g0 < g1)
    int bg = b * NGRP + g0;
    uint4 a0c  = A0p[bg * 64 + lane];
    uint4 a1ac = A1p[(bg * 2 + 0) * 64 + lane];
    uint4 a1bc = A1p[(bg * 2 + 1) * 64 + lane];

    // main loop: prefetch g+1 (in-range by construction), compute g, rotate
    for (int g = g0; g < g1 - 1; ++g, ++bg) {
        uint4 a0n  = A0p[(bg + 1) * 64 + lane];
        uint4 a1an = A1p[((bg + 1) * 2 + 0) * 64 + lane];
        uint4 a1bn = A1p[((bg + 1) * 2 + 1) * 64 + lane];

        group_body(g, bg, a0c, a1ac, a1bc);

        a0c = a0n; a1ac = a1an; a1bc = a1bn;
    }
    // peeled last group: no prefetch, no undef values anywhere
    group_body(g1 - 1, bg, a0c, a1ac, a1bc);
}

extern "C" void kernel_launch(void* const* d_in, const int* in_sizes, int n_in,
                              void* d_out, int out_size, void* d_ws, size_t ws_size,
                              hipStream_t stream) {
    const float* seg_feat    = (const float*)d_in[0];
    const float* conv_weight = (const float*)d_in[1];
    const int*   ind         = (const int*)d_in[2];
    float*       out         = (float*)d_out;

    u32*   A0 = (u32*)d_ws;                                 // 102400 B
    u32*   A1 = (u32*)((char*)d_ws + 102400);               // 204800 B
    float* WT = (float*)((char*)d_ws + 307200);             // 32000 B

    {
        dim3 grid((84800 + 255) / 256), block(256);
        pack_kernel<<<grid, block, 0, stream>>>(conv_weight, ind, A0, A1, WT);
    }
    {
        dim3 grid(256, 4, 4), block(64);    // 4096 single-wave blocks
        mfma_kernel<<<grid, block, 0, stream>>>(seg_feat, A0, A1, WT, out);
    }
}